// Round 10
// baseline (150.919 us; speedup 1.0000x reference)
//
#include <hip/hip_runtime.h>

#define BS 8
#define SEQ 512
#define CDIM 512
#define NC 5
#define IMG_H 768
#define IMG_W 768
#define HW (IMG_H * IMG_W)
#define NTOK (BS * SEQ)

// R10 = R9 (best: 146.3 us) with 2x wave concurrency on the gather.
// Theory: gather is miss-concurrency (MSHR) bound -- 16 waves/CU in R2-R9
// left half the wave capacity idle. Now: 128-thread blocks (2 waves), one
// token per block, 4096 blocks -> 16 blocks/CU x 2 waves = 32 waves/CU
// (full). Wave w covers box rows y0+w, y0+w+2, ... (even/odd split).
// XCD swizzle kept: batch = blockIdx & 7 pins each image to one XCD L2.
// Exec-masked loads kept (R7 lesson: clamping inflates footprint 2.5x).
__global__ __launch_bounds__(128) void token_kernel(
    const float* __restrict__ emb,     // [BS, SEQ, CDIM]
    const float* __restrict__ cls,     // [BS, NC, H, W]
    const float* __restrict__ Wc,      // [NC, CDIM]
    const float* __restrict__ bc,      // [NC]
    const int*   __restrict__ coords,  // [BS, SEQ, 4] (x0,y0,x1,y1)
    const int*   __restrict__ mask,    // [BS, SEQ]
    float2* __restrict__ ws)           // [NTOK] block partial (nll*m, m)
{
    const int t     = threadIdx.x;     // 0..127
    const int wave  = t >> 6;          // 0 or 1
    const int lane  = t & 63;
    // XCD-affinity swizzle: batch = blockIdx & 7, slot = blockIdx >> 3
    const int b     = blockIdx.x & 7;
    const int token = (b << 9) + (blockIdx.x >> 3);

    int x0 = coords[token * 4 + 0];
    int y0 = coords[token * 4 + 1];
    int x1 = coords[token * 4 + 2];
    int y1 = coords[token * 4 + 3];
    if (y1 == y0) y1++;            // degenerate-box fix (reference semantics)
    if (x1 == x0) x1++;
    if (x1 > IMG_W) x1 = IMG_W;
    if (y1 > IMG_H) y1 = IMG_H;

    // ---- box histogram: x = x0+lane (exec-masked), rows split by wave ----
    unsigned long long hp = 0ull;  // packed hist: class c in bits [12c,12c+12)
    {
        const int xx = x0 + lane;
        const bool xok = (xx < x1);            // width <= 63 -> one col step
        const float* p0 = cls + (size_t)b * NC * HW + (y0 + wave) * IMG_W + xx;
#pragma unroll 4
        for (int yy = y0 + wave; yy < y1; yy += 2, p0 += 2 * IMG_W) {
            if (xok) {
                const float v0 = p0[0 * HW];
                const float v1 = p0[1 * HW];
                const float v2 = p0[2 * HW];
                const float v3 = p0[3 * HW];
                const float v4 = p0[4 * HW];
                int lab = 0; float best = v0;  // strict > == first-max
                if (v1 > best) { best = v1; lab = 1; }
                if (v2 > best) { best = v2; lab = 2; }
                if (v3 > best) { best = v3; lab = 3; }
                if (v4 > best) { best = v4; lab = 4; }
                hp += 1ull << (lab * 12);
            }
        }
    }

    // ---- logits partials: 4 emb elems / thread (float4), 128 threads ----
    const float4 e0 = *(const float4*)(emb + (size_t)token * CDIM + t * 4);
    float part[NC];
#pragma unroll
    for (int c = 0; c < NC; ++c) {
        const float4 w0 = *(const float4*)(Wc + c * CDIM + t * 4);
        part[c] = e0.x * w0.x + e0.y * w0.y + e0.z * w0.z + e0.w * w0.w;
    }

    // ---- wave reduce (5 floats + 1 ull) ----
#pragma unroll
    for (int off = 32; off >= 1; off >>= 1) {
#pragma unroll
        for (int c = 0; c < NC; ++c) part[c] += __shfl_down(part[c], off);
        hp += __shfl_down(hp, off);
    }

    // ---- combine the 2 waves via LDS ----
    __shared__ float              s_part[2][NC];
    __shared__ unsigned long long s_hp[2];
    if (lane == 0) {
#pragma unroll
        for (int c = 0; c < NC; ++c) s_part[wave][c] = part[c];
        s_hp[wave] = hp;
    }
    __syncthreads();

    if (t == 0) {
        const unsigned long long h = s_hp[0] + s_hp[1];
        float l[NC];
#pragma unroll
        for (int c = 0; c < NC; ++c)
            l[c] = s_part[0][c] + s_part[1][c] + bc[c];

        int maj = 0;
        int bestc = (int)(h & 4095);
#pragma unroll
        for (int c = 1; c < NC; ++c) {
            const int hc = (int)((h >> (12 * c)) & 4095);
            if (hc > bestc) { bestc = hc; maj = c; }   // first-max tiebreak
        }

        float m = l[0];
#pragma unroll
        for (int c = 1; c < NC; ++c) m = fmaxf(m, l[c]);
        float s = 0.0f;
#pragma unroll
        for (int c = 0; c < NC; ++c) s += __expf(l[c] - m);
        const float nll = m + __logf(s) - l[maj];

        const float mk = (mask[token] == 1) ? 1.0f : 0.0f;
        ws[blockIdx.x] = make_float2(nll * mk, mk);
    }
}

__global__ __launch_bounds__(256) void finalize_kernel(
    const float2* __restrict__ ws, float* __restrict__ out)
{
    float a = 0.0f, bsum = 0.0f;
#pragma unroll
    for (int i = threadIdx.x; i < NTOK; i += 256) {
        const float2 v = ws[i];
        a += v.x; bsum += v.y;
    }
#pragma unroll
    for (int off = 32; off >= 1; off >>= 1) {
        a    += __shfl_down(a, off);
        bsum += __shfl_down(bsum, off);
    }
    __shared__ float sa[4], sb[4];
    const int wave = threadIdx.x >> 6;
    if ((threadIdx.x & 63) == 0) { sa[wave] = a; sb[wave] = bsum; }
    __syncthreads();
    if (threadIdx.x == 0) {
        a    = sa[0] + sa[1] + sa[2] + sa[3];
        bsum = sb[0] + sb[1] + sb[2] + sb[3];
        out[0] = a / bsum;
    }
}

extern "C" void kernel_launch(void* const* d_in, const int* in_sizes, int n_in,
                              void* d_out, int out_size, void* d_ws, size_t ws_size,
                              hipStream_t stream) {
    const float* emb    = (const float*)d_in[0];  // [8,512,512] f32
    const float* cls    = (const float*)d_in[1];  // [8,5,768,768] f32
    const float* Wc     = (const float*)d_in[2];  // [5,512] f32
    const float* bc     = (const float*)d_in[3];  // [5] f32
    const int*   coords = (const int*)d_in[4];    // [8,512,4] i32
    const int*   mask   = (const int*)d_in[5];    // [8,512] i32
    float* out = (float*)d_out;
    float2* ws = (float2*)d_ws;                   // NTOK float2 partials

    token_kernel<<<NTOK, 128, 0, stream>>>(emb, cls, Wc, bc, coords, mask, ws);
    finalize_kernel<<<1, 256, 0, stream>>>(ws, out);
}

// Round 11
// 146.968 us; speedup vs baseline: 1.0269x; 1.0269x over previous
//
#include <hip/hip_runtime.h>

#define BS 8
#define SEQ 512
#define CDIM 512
#define NC 5
#define IMG_H 768
#define IMG_W 768
#define HW (IMG_H * IMG_W)
#define NTOK (BS * SEQ)
#define NBLK (NTOK / 4)   // 1024 blocks = 4/CU, all co-resident, one round

// R11 = R9 (best measured: 146.3 us) + hoisted loop-invariant predicate.
// Final structure after 10 rounds of measurement:
//  - Direct per-box gather (23.5 MB of random 64B lines) measured ~27-31 us
//    across SIX structural variants (1 or 4 waves/token, one-shot, float4
//    slots, 2x concurrency) -> it runs at the random-line HBM rate
//    (~0.87 TB/s), a memory-system floor, not a kernel-structure artifact.
//  - Label-map two-pass (random->streaming conversion): +36 us, worse (R5/R6).
//  - Single-kernel ticket fusion: +28 us (1024 device-scope fences), worse (R8).
//  - 2x wave concurrency: +4.6 us, worse (R10).
//  - XCD swizzle (batch = blockIdx & 7 pins each image to one XCD L2): -1 us.
//  - Exec-masked loads (masked lanes issue NO vmem) beat address-clamped
//    unconditional loads by ~28 us of footprint inflation (R7).
__global__ __launch_bounds__(256) void token_kernel(
    const float* __restrict__ emb,     // [BS, SEQ, CDIM]
    const float* __restrict__ cls,     // [BS, NC, H, W]
    const float* __restrict__ Wc,      // [NC, CDIM]
    const float* __restrict__ bc,      // [NC]
    const int*   __restrict__ coords,  // [BS, SEQ, 4] (x0,y0,x1,y1)
    const int*   __restrict__ mask,    // [BS, SEQ]
    float2* __restrict__ ws)           // [NBLK] block partial (nll*m, m)
{
    const int t     = threadIdx.x;
    const int wave  = t >> 6;
    const int lane  = t & 63;
    // XCD-affinity: batch = blockIdx & 7, slot within batch = blockIdx >> 3
    const int b     = blockIdx.x & 7;
    const int slot  = blockIdx.x >> 3;            // 0..127
    const int token = (b << 9) + slot * 4 + wave; // batch-local 4-token group

    int x0 = coords[token * 4 + 0];
    int y0 = coords[token * 4 + 1];
    int x1 = coords[token * 4 + 2];
    int y1 = coords[token * 4 + 3];
    if (y1 == y0) y1++;            // degenerate-box fix (reference semantics)
    if (x1 == x0) x1++;
    if (x1 > IMG_W) x1 = IMG_W;
    if (y1 > IMG_H) y1 = IMG_H;

    // ---- box histogram: x = x0+lane, exec-masked; predicate hoisted out of
    // the row loop (x0..y1 are wave-uniform -> exec set once, rows pipeline
    // with no per-iteration mask churn). ----
    unsigned long long hp = 0ull;  // packed hist: class c in bits [12c,12c+12)
    {
        const int xx = x0 + lane;
        const float* p0 = cls + (size_t)b * NC * HW + y0 * IMG_W + xx;
        if (xx < x1) {                 // loop-invariant: one exec-mask set
#pragma unroll 4
            for (int yy = y0; yy < y1; ++yy, p0 += IMG_W) {
                const float v0 = p0[0 * HW];
                const float v1 = p0[1 * HW];
                const float v2 = p0[2 * HW];
                const float v3 = p0[3 * HW];
                const float v4 = p0[4 * HW];
                int lab = 0; float best = v0;  // strict > == first-max
                if (v1 > best) { best = v1; lab = 1; }
                if (v2 > best) { best = v2; lab = 2; }
                if (v3 > best) { best = v3; lab = 3; }
                if (v4 > best) { best = v4; lab = 4; }
                hp += 1ull << (lab * 12);
            }
        }
    }

    // ---- logits partials: 8 emb elems / lane vs 5 rows (Wc L1-hot) ----
    const float* e = emb + (size_t)token * CDIM + lane * 8;
    const float4 e0 = *(const float4*)(e);
    const float4 e1 = *(const float4*)(e + 4);
    float part[NC];
#pragma unroll
    for (int c = 0; c < NC; ++c) {
        const float* w = Wc + c * CDIM + lane * 8;
        const float4 w0 = *(const float4*)(w);
        const float4 w1 = *(const float4*)(w + 4);
        part[c] = e0.x * w0.x + e0.y * w0.y + e0.z * w0.z + e0.w * w0.w
                + e1.x * w1.x + e1.y * w1.y + e1.z * w1.z + e1.w * w1.w;
    }

    // ---- wave reduce (5 floats + 1 ull) ----
#pragma unroll
    for (int off = 32; off >= 1; off >>= 1) {
#pragma unroll
        for (int c = 0; c < NC; ++c) part[c] += __shfl_down(part[c], off);
        hp += __shfl_down(hp, off);
    }

    __shared__ float2 s_pair[4];
    if (lane == 0) {
        float l[NC];
#pragma unroll
        for (int c = 0; c < NC; ++c) l[c] = part[c] + bc[c];

        int maj = 0;
        int bestc = (int)(hp & 4095);
#pragma unroll
        for (int c = 1; c < NC; ++c) {
            const int hc = (int)((hp >> (12 * c)) & 4095);
            if (hc > bestc) { bestc = hc; maj = c; }   // first-max tiebreak
        }

        float m = l[0];
#pragma unroll
        for (int c = 1; c < NC; ++c) m = fmaxf(m, l[c]);
        float s = 0.0f;
#pragma unroll
        for (int c = 0; c < NC; ++c) s += __expf(l[c] - m);
        const float nll = m + __logf(s) - l[maj];

        const float mk = (mask[token] == 1) ? 1.0f : 0.0f;
        s_pair[wave] = make_float2(nll * mk, mk);
    }
    __syncthreads();

    if (t == 0) {
        const float2 a = s_pair[0], b2 = s_pair[1],
                     c2 = s_pair[2], d2 = s_pair[3];
        ws[blockIdx.x] = make_float2(a.x + b2.x + c2.x + d2.x,
                                     a.y + b2.y + c2.y + d2.y);
    }
}

__global__ __launch_bounds__(256) void finalize_kernel(
    const float2* __restrict__ ws, float* __restrict__ out)
{
    float a = 0.0f, bsum = 0.0f;
#pragma unroll
    for (int i = threadIdx.x; i < NBLK; i += 256) {
        const float2 v = ws[i];
        a += v.x; bsum += v.y;
    }
#pragma unroll
    for (int off = 32; off >= 1; off >>= 1) {
        a    += __shfl_down(a, off);
        bsum += __shfl_down(bsum, off);
    }
    __shared__ float sa[4], sb[4];
    const int wave = threadIdx.x >> 6;
    if ((threadIdx.x & 63) == 0) { sa[wave] = a; sb[wave] = bsum; }
    __syncthreads();
    if (threadIdx.x == 0) {
        a    = sa[0] + sa[1] + sa[2] + sa[3];
        bsum = sb[0] + sb[1] + sb[2] + sb[3];
        out[0] = a / bsum;
    }
}

extern "C" void kernel_launch(void* const* d_in, const int* in_sizes, int n_in,
                              void* d_out, int out_size, void* d_ws, size_t ws_size,
                              hipStream_t stream) {
    const float* emb    = (const float*)d_in[0];  // [8,512,512] f32
    const float* cls    = (const float*)d_in[1];  // [8,5,768,768] f32
    const float* Wc     = (const float*)d_in[2];  // [5,512] f32
    const float* bc     = (const float*)d_in[3];  // [5] f32
    const int*   coords = (const int*)d_in[4];    // [8,512,4] i32
    const int*   mask   = (const int*)d_in[5];    // [8,512] i32
    float* out = (float*)d_out;
    float2* ws = (float2*)d_ws;                   // NBLK float2 partials

    token_kernel<<<NBLK, 256, 0, stream>>>(emb, cls, Wc, bc, coords, mask, ws);
    finalize_kernel<<<1, 256, 0, stream>>>(ws, out);
}